// Round 8
// baseline (104.556 us; speedup 1.0000x reference)
//
#include <hip/hip_runtime.h>
#include <hip/hip_bf16.h>
#include <stdint.h>

#define NFEATS 128

typedef __attribute__((ext_vector_type(8))) short bf16x8;
typedef __attribute__((ext_vector_type(4))) float f32x4;
typedef __attribute__((ext_vector_type(4))) short short4v;

__device__ inline short f2bf(float f) {
    union { float f; unsigned u; } c; c.f = f;
    unsigned u = c.u;
    return (short)((u + 0x7FFFu + ((u >> 16) & 1u)) >> 16);  // RNE
}
__device__ inline float bf2f(short v) {
    union { unsigned u; float f; } c;
    c.u = ((unsigned)(unsigned short)v) << 16;
    return c.f;
}

#define WAITCNT_CASE(N) asm volatile("s_waitcnt vmcnt(" #N ")" ::: "memory")
__device__ inline void wait_vmcnt(int allowed) {
    switch (allowed) {
        case 0:  WAITCNT_CASE(0);  break;
        case 2:  WAITCNT_CASE(2);  break;
        case 8:  WAITCNT_CASE(8);  break;
        case 10: WAITCNT_CASE(10); break;
        case 16: WAITCNT_CASE(16); break;
        default: WAITCNT_CASE(18); break;   // steady state
    }
}

// Fused precompute for both tables (blockIdx.y selects):
//   y == 0: A[n,j] = sum_k item[n,k] * W1[j,   k] + b1[j]
//   y == 1: B[n,j] = sum_k user[n,k] * W1[j,128+k]
// Depth-2 software pipeline: 3 rotating 16KB LDS buffers (32-row X tiles),
// counted s_waitcnt vmcnt(N) + raw s_barrier so the NEXT tile's
// global_load_lds and the previous tile's C-stores stay in flight across
// the barrier (no vmcnt(0) drain). 48KB LDS -> 3 blocks/CU = 24 waves/CU.
// Wave (8) = rowgrp(2) x colquarter(4): 16 rows x 32 cols per wave,
// 8 MFMA per tile per wave. Per wave per tile: 2 global_load_lds, 8 stores.
__global__ __launch_bounds__(512, 6) void precompute_kernel(
    const float* __restrict__ item, const float* __restrict__ user,
    const float* __restrict__ W1, const float* __restrict__ b1,
    short* __restrict__ A, short* __restrict__ B, int n_nodes)
{
    __shared__ __align__(1024) uint8_t lds[3 * 16384];

    const int which = blockIdx.y;
    const float* __restrict__ X = which ? user : item;
    short* __restrict__ Out = which ? B : A;
    const int k_off4 = which ? 32 : 0;   // in float4 units (128 floats)

    const int tid = threadIdx.x;
    const int w = tid >> 6, lane = tid & 63;
    const int r16 = lane & 15, q = lane >> 4;     // q in 0..3
    const int rowgrp = w >> 2, colq = w & 3;      // 2 x 4

    // ---- stage W (fp32 -> bf16) into bufs 0+1 region (32KB), swizzled ----
    // Row j (256B): 16B-chunk c stored at j*256 + ((c ^ (j&7))<<4)
    {
        const float4* W4 = (const float4*)W1;     // row stride 64 float4
        for (int i = tid; i < 128 * 32; i += 512) {
            int j = i >> 5, c4 = i & 31;
            float4 wv = W4[j * 64 + k_off4 + c4];
            short4v p;
            p[0] = f2bf(wv.x); p[1] = f2bf(wv.y); p[2] = f2bf(wv.z); p[3] = f2bf(wv.w);
            int ch = c4 >> 1, sub = (c4 & 1) * 8;
            *(short4v*)(lds + j * 256 + ((ch ^ (j & 7)) << 4) + sub) = p;
        }
    }
    __syncthreads();

    // ---- lift this wave's W fragments + bias into registers ----
    bf16x8 wfrag[2][4];
    f32x4 bias4[2];
#pragma unroll
    for (int n = 0; n < 2; ++n) {
        int col = colq * 32 + n * 16 + r16;
#pragma unroll
        for (int kk = 0; kk < 4; ++kk) {
            int ch = kk * 4 + q;
            wfrag[n][kk] = *(const bf16x8*)(lds + col * 256 + ((ch ^ (col & 7)) << 4));
        }
        float bv = which ? 0.f : b1[col];
        f32x4 init = {bv, bv, bv, bv};
        bias4[n] = init;
    }
    __syncthreads();   // whole LDS now reusable as X buffers

    const int n_tiles = (n_nodes + 31) >> 5;     // 32-row tiles
    const int G = gridDim.x;

    // Stage one 32-row X tile into buffer b (linear LDS dest, swizzled src).
    // X[row r][16B-chunk c] lives at LDS r*512 + ((c ^ (r&7))<<4).
    auto stage = [&](int b, int t) {
        uint8_t* base = lds + b * 16384;
#pragma unroll
        for (int i = 0; i < 2; ++i) {
            int o = (w << 11) + (i << 10) + (lane << 4);   // linear byte off
            int r = o >> 9;
            int c_lds = (o >> 4) & 31;
            int node = (t << 5) + r;
            if (node >= n_nodes) node = n_nodes - 1;       // clamp
            const uint8_t* gp = (const uint8_t*)X + (size_t)node * 512
                              + (size_t)(((c_lds ^ (r & 7)) << 4));
            auto g1 = (const __attribute__((address_space(1))) uint32_t*)gp;
            auto l3 = (__attribute__((address_space(3))) uint32_t*)(base + (w << 11) + (i << 10));
            __builtin_amdgcn_global_load_lds(g1, l3, 16, 0, 0);
        }
    };

    const int t0 = blockIdx.x;
    if (t0 < n_tiles) stage(0, t0);
    if (t0 + G < n_tiles) stage(1, t0 + G);

    int b = 0;
    int nst = 0;          // outstanding store batches (capped at 2)
    for (int t = t0; t < n_tiles; t += G) {
        // wait for CURRENT tile's loads only: allowed = 2*ahead + 8*nst
        const int ahead = (t + G < n_tiles) ? 1 : 0;
        __builtin_amdgcn_sched_barrier(0);
        wait_vmcnt(ahead * 2 + nst * 8);
        __builtin_amdgcn_s_barrier();
        __builtin_amdgcn_sched_barrier(0);

        // stage tile t+2G into the buffer being freed (safe: all waves passed
        // the barrier, so no one still reads buf[(b+2)%3] from iter t-G)
        int t2 = t + 2 * G;
        if (t2 < n_tiles) stage((b + 2) % 3 == 2 ? 2 : (b + 2) % 3, t2);

        // ---- X fragments from buf b (swizzled ds_read_b128) ----
        const uint8_t* base = lds + b * 16384;
        const int r = rowgrp * 16 + r16;
        const uint8_t* rowp = base + r * 512;
        const int s = r & 7;
        bf16x8 afrag[4];
#pragma unroll
        for (int kk = 0; kk < 4; ++kk) {
            int c0 = kk * 8 + q * 2;
            float4 v0 = *(const float4*)(rowp + ((c0 ^ s) << 4));
            float4 v1 = *(const float4*)(rowp + (((c0 + 1) ^ s) << 4));
            bf16x8 f;
            f[0] = f2bf(v0.x); f[1] = f2bf(v0.y); f[2] = f2bf(v0.z); f[3] = f2bf(v0.w);
            f[4] = f2bf(v1.x); f[5] = f2bf(v1.y); f[6] = f2bf(v1.z); f[7] = f2bf(v1.w);
            afrag[kk] = f;
        }

        // ---- MFMA: D[node-row][col], col = lane&15 block ----
        f32x4 acc[2];
#pragma unroll
        for (int n = 0; n < 2; ++n) acc[n] = bias4[n];
#pragma unroll
        for (int n = 0; n < 2; ++n)
#pragma unroll
            for (int kk = 0; kk < 4; ++kk)
                acc[n] = __builtin_amdgcn_mfma_f32_16x16x32_bf16(afrag[kk], wfrag[n][kk], acc[n], 0, 0, 0);

        // ---- C-write (R5 pattern): row = (lane>>4)*4 + rr, col = n*16+r16 ----
        const int row0 = (t << 5) + rowgrp * 16 + q * 4;
#pragma unroll
        for (int rr = 0; rr < 4; ++rr) {
            int row = row0 + rr;
            if (row < n_nodes) {
                short* orow = Out + (size_t)row * NFEATS + colq * 32;
#pragma unroll
                for (int n = 0; n < 2; ++n)
                    orow[n * 16 + r16] = f2bf(acc[n][rr]);
            }
        }

        nst = nst < 2 ? nst + 1 : 2;
        b = (b == 2) ? 0 : b + 1;
    }
}

// Edge stage: score[e] = dot(relu(A[src[e]] + B[dst[e]]), w2) + b2
// One quarter-wave (16 lanes) per edge, 2 edges in flight per iteration.
__global__ __launch_bounds__(256) void edge_kernel(
    const short* __restrict__ A, const short* __restrict__ B,
    const int* __restrict__ src, const int* __restrict__ dst,
    const float* __restrict__ W2, const float* __restrict__ b2,
    float* __restrict__ out, int n_edges)
{
    const int t = blockIdx.x * 256 + threadIdx.x;
    const int lane16 = threadIdx.x & 15;

    float w2v[8];
#pragma unroll
    for (int j = 0; j < 8; ++j) w2v[j] = W2[lane16 * 8 + j];
    const float b2v = b2[0];

    const int qw = t >> 4;
    const int nqw = (gridDim.x * 256) >> 4;

    for (int e0 = qw; e0 < n_edges; e0 += 2 * nqw) {
        const int e1 = e0 + nqw;
        const bool has1 = e1 < n_edges;

        int s0 = src[e0], d0 = dst[e0];
        int s1 = has1 ? src[e1] : s0;
        int d1 = has1 ? dst[e1] : d0;

        bf16x8 av0 = *(const bf16x8*)(A + (size_t)s0 * NFEATS + lane16 * 8);
        bf16x8 bv0 = *(const bf16x8*)(B + (size_t)d0 * NFEATS + lane16 * 8);
        bf16x8 av1 = *(const bf16x8*)(A + (size_t)s1 * NFEATS + lane16 * 8);
        bf16x8 bv1 = *(const bf16x8*)(B + (size_t)d1 * NFEATS + lane16 * 8);

        float acc0 = 0.f, acc1 = 0.f;
#pragma unroll
        for (int j = 0; j < 8; ++j) {
            float h0 = bf2f(av0[j]) + bf2f(bv0[j]);
            h0 = fmaxf(h0, 0.f);
            acc0 = fmaf(h0, w2v[j], acc0);
            float h1 = bf2f(av1[j]) + bf2f(bv1[j]);
            h1 = fmaxf(h1, 0.f);
            acc1 = fmaf(h1, w2v[j], acc1);
        }
#pragma unroll
        for (int sh = 1; sh <= 8; sh <<= 1) {
            acc0 += __shfl_xor(acc0, sh);
            acc1 += __shfl_xor(acc1, sh);
        }
        if (lane16 == 0) {
            out[e0] = acc0 + b2v;
            if (has1) out[e1] = acc1 + b2v;
        }
    }
}

extern "C" void kernel_launch(void* const* d_in, const int* in_sizes, int n_in,
                              void* d_out, int out_size, void* d_ws, size_t ws_size,
                              hipStream_t stream) {
    const float* item = (const float*)d_in[0];
    const float* user = (const float*)d_in[1];
    const float* W1   = (const float*)d_in[2];
    const float* b1   = (const float*)d_in[3];
    const float* W2   = (const float*)d_in[4];
    const float* b2   = (const float*)d_in[5];
    const int*   src  = (const int*)d_in[6];
    const int*   dst  = (const int*)d_in[7];
    float* out = (float*)d_out;

    const int n_nodes = in_sizes[0] / NFEATS;
    const int n_edges = in_sizes[6];

    short* A = (short*)d_ws;                         // [n_nodes][128] bf16
    short* B = A + (size_t)n_nodes * NFEATS;         // [n_nodes][128] bf16

    dim3 grid(384, 2);                               // 768 blocks = 3/CU resident
    precompute_kernel<<<grid, 512, 0, stream>>>(item, user, W1, b1, A, B, n_nodes);

    edge_kernel<<<2048, 256, 0, stream>>>(A, B, src, dst, W2, b2, out, n_edges);
}

// Round 9
// 81.589 us; speedup vs baseline: 1.2815x; 1.2815x over previous
//
#include <hip/hip_runtime.h>
#include <hip/hip_bf16.h>
#include <stdint.h>

#define NFEATS 128

typedef __attribute__((ext_vector_type(8))) short bf16x8;
typedef __attribute__((ext_vector_type(4))) float f32x4;
typedef __attribute__((ext_vector_type(4))) short short4v;

__device__ inline short f2bf(float f) {
    union { float f; unsigned u; } c; c.f = f;
    unsigned u = c.u;
    return (short)((u + 0x7FFFu + ((u >> 16) & 1u)) >> 16);  // RNE
}
__device__ inline float bf2f(short v) {
    union { unsigned u; float f; } c;
    c.u = ((unsigned)(unsigned short)v) << 16;
    return c.f;
}

// Fused precompute for both tables (blockIdx.y selects):
//   y == 0: A[n,j] = sum_k item[n,k] * W1[j,   k] + b1[j]
//   y == 1: B[n,j] = sum_k user[n,k] * W1[j,128+k]
// EXACT Round-5 structure (best measured: 47.5us steady). ONE change:
// per-tile __syncthreads() (implicit vmcnt(0) drain of prev tile's 16
// C-stores + staging loads) replaced by counted s_waitcnt vmcnt(16) +
// raw s_barrier, so the previous tile's stores retire in the shadow of
// the next tile's compute. vmcnt accounting per wave per tile:
//   [4 staging loads (older)] [16 C-stores (newer)] -> wait vmcnt(16)
// drains exactly the staging loads. Stores are branch-hoisted
// unconditional on full tiles so exactly 16 are counted; a non-full
// previous tile (tail only) or first iteration uses vmcnt(0).
__global__ __launch_bounds__(512, 4) void precompute_kernel(
    const float* __restrict__ item, const float* __restrict__ user,
    const float* __restrict__ W1, const float* __restrict__ b1,
    short* __restrict__ A, short* __restrict__ B, int n_nodes)
{
    __shared__ __align__(1024) uint8_t lds[34816 + 32768];  // [W/buf0 | buf1]

    const int which = blockIdx.y;
    const float* __restrict__ X = which ? user : item;
    short* __restrict__ Out = which ? B : A;
    const int k_off4 = which ? 32 : 0;   // in float4 units (128 floats)

    const int tid = threadIdx.x;
    const int w = tid >> 6, lane = tid & 63;
    const int r16 = lane & 15, q = lane >> 4;     // q in 0..3
    const int rowgrp = w >> 1, colhalf = w & 1;

    // ---- stage W (fp32 -> bf16) into padded LDS ----
    {
        short (*Wl)[136] = (short (*)[136])lds;
        const float4* W4 = (const float4*)W1;     // row stride 64 float4
        for (int i = tid; i < 128 * 32; i += 512) {
            int j = i >> 5, c = i & 31;
            float4 wv = W4[j * 64 + k_off4 + c];
            short4v p;
            p[0] = f2bf(wv.x); p[1] = f2bf(wv.y); p[2] = f2bf(wv.z); p[3] = f2bf(wv.w);
            *(short4v*)&Wl[j][c * 4] = p;
        }
    }
    __syncthreads();

    // ---- lift this wave's W fragments + bias into registers ----
    bf16x8 wfrag[4][4];
    float bias[4];
    {
        short (*Wl)[136] = (short (*)[136])lds;
#pragma unroll
        for (int n = 0; n < 4; ++n) {
            int col = colhalf * 64 + n * 16 + r16;
#pragma unroll
            for (int kk = 0; kk < 4; ++kk)
                wfrag[n][kk] = *(const bf16x8*)&Wl[col][kk * 32 + q * 8];
            bias[n] = which ? 0.f : b1[col];
        }
    }
    __syncthreads();   // W region now reusable as X buffer 0

    const int n_tiles = (n_nodes + 63) >> 6;

    // Stage one 64-row tile into buffer `buf` (linear LDS, swizzled global src).
    // Storage rule: X[row r][16B-chunk c] lives at LDS r*512 + (c^(r&7))*16.
    auto stage = [&](int buf, int t) {
        uint8_t* base = lds + buf * 34816;
#pragma unroll
        for (int i = 0; i < 4; ++i) {
            int o = (w << 12) + (i << 10) + (lane << 4);   // linear byte off in tile
            int r = o >> 9;
            int c_lds = (o >> 4) & 31;
            int node = (t << 6) + r;
            if (node >= n_nodes) node = n_nodes - 1;       // clamp (stores predicated)
            const uint8_t* gp = (const uint8_t*)X + (size_t)node * 512
                              + (size_t)(((c_lds ^ (r & 7)) << 4));
            auto g1 = (const __attribute__((address_space(1))) uint32_t*)gp;
            auto l3 = (__attribute__((address_space(3))) uint32_t*)(base + (w << 12) + (i << 10));
            __builtin_amdgcn_global_load_lds(g1, l3, 16, 0, 0);
        }
    };

    int t = blockIdx.x;
    if (t < n_tiles) stage(0, t);
    int cur = 0;
    bool prev_full = false;   // first barrier must drain everything

    for (; t < n_tiles; t += gridDim.x) {
        // ---- counted-vmcnt barrier (T4): keep prev tile's stores in flight ----
        __builtin_amdgcn_sched_barrier(0);
        if (prev_full) {
            asm volatile("s_waitcnt vmcnt(16) lgkmcnt(0)" ::: "memory");
        } else {
            asm volatile("s_waitcnt vmcnt(0) lgkmcnt(0)" ::: "memory");
        }
        __builtin_amdgcn_sched_barrier(0);
        __builtin_amdgcn_s_barrier();
        __builtin_amdgcn_sched_barrier(0);

        int tn = t + gridDim.x;
        if (tn < n_tiles) stage(cur ^ 1, tn);    // async prefetch next tile

        // ---- fragments from buf[cur] (swizzled ds_read_b128) ----
        const uint8_t* base = lds + cur * 34816;
        const int r = rowgrp * 16 + r16;
        const uint8_t* rowp = base + r * 512;
        const int s = r & 7;
        bf16x8 afrag[4];
#pragma unroll
        for (int kk = 0; kk < 4; ++kk) {
            int c0 = kk * 8 + q * 2;
            float4 v0 = *(const float4*)(rowp + ((c0 ^ s) << 4));
            float4 v1 = *(const float4*)(rowp + (((c0 + 1) ^ s) << 4));
            bf16x8 f;
            f[0] = f2bf(v0.x); f[1] = f2bf(v0.y); f[2] = f2bf(v0.z); f[3] = f2bf(v0.w);
            f[4] = f2bf(v1.x); f[5] = f2bf(v1.y); f[6] = f2bf(v1.z); f[7] = f2bf(v1.w);
            afrag[kk] = f;
        }

        f32x4 acc[4];
#pragma unroll
        for (int n = 0; n < 4; ++n) {
            f32x4 init = {bias[n], bias[n], bias[n], bias[n]};
            acc[n] = init;
        }
#pragma unroll
        for (int n = 0; n < 4; ++n)
#pragma unroll
            for (int kk = 0; kk < 4; ++kk)
                acc[n] = __builtin_amdgcn_mfma_f32_16x16x32_bf16(afrag[kk], wfrag[n][kk], acc[n], 0, 0, 0);

        // ---- C-write: row = (lane>>4)*4 + rr, col = colhalf*64 + n*16 + r16 ----
        const bool full = ((t + 1) << 6) <= n_nodes;   // wave-uniform
        const int row0 = (t << 6) + rowgrp * 16 + q * 4;
        if (full) {
            // unconditional: exactly 16 counted vmem stores
#pragma unroll
            for (int rr = 0; rr < 4; ++rr) {
                short* orow = Out + (size_t)(row0 + rr) * NFEATS;
#pragma unroll
                for (int n = 0; n < 4; ++n)
                    orow[colhalf * 64 + n * 16 + r16] = f2bf(acc[n][rr]);
            }
        } else {
#pragma unroll
            for (int rr = 0; rr < 4; ++rr) {
                int row = row0 + rr;
                if (row < n_nodes) {
                    short* orow = Out + (size_t)row * NFEATS;
#pragma unroll
                    for (int n = 0; n < 4; ++n)
                        orow[colhalf * 64 + n * 16 + r16] = f2bf(acc[n][rr]);
                }
            }
        }
        prev_full = full;
        cur ^= 1;
    }
}

// Edge stage: score[e] = dot(relu(A[src[e]] + B[dst[e]]), w2) + b2
// One quarter-wave (16 lanes) per edge, 2 edges in flight per iteration.
__global__ __launch_bounds__(256) void edge_kernel(
    const short* __restrict__ A, const short* __restrict__ B,
    const int* __restrict__ src, const int* __restrict__ dst,
    const float* __restrict__ W2, const float* __restrict__ b2,
    float* __restrict__ out, int n_edges)
{
    const int t = blockIdx.x * 256 + threadIdx.x;
    const int lane16 = threadIdx.x & 15;

    float w2v[8];
#pragma unroll
    for (int j = 0; j < 8; ++j) w2v[j] = W2[lane16 * 8 + j];
    const float b2v = b2[0];

    const int qw = t >> 4;
    const int nqw = (gridDim.x * 256) >> 4;

    for (int e0 = qw; e0 < n_edges; e0 += 2 * nqw) {
        const int e1 = e0 + nqw;
        const bool has1 = e1 < n_edges;

        int s0 = src[e0], d0 = dst[e0];
        int s1 = has1 ? src[e1] : s0;
        int d1 = has1 ? dst[e1] : d0;

        bf16x8 av0 = *(const bf16x8*)(A + (size_t)s0 * NFEATS + lane16 * 8);
        bf16x8 bv0 = *(const bf16x8*)(B + (size_t)d0 * NFEATS + lane16 * 8);
        bf16x8 av1 = *(const bf16x8*)(A + (size_t)s1 * NFEATS + lane16 * 8);
        bf16x8 bv1 = *(const bf16x8*)(B + (size_t)d1 * NFEATS + lane16 * 8);

        float acc0 = 0.f, acc1 = 0.f;
#pragma unroll
        for (int j = 0; j < 8; ++j) {
            float h0 = bf2f(av0[j]) + bf2f(bv0[j]);
            h0 = fmaxf(h0, 0.f);
            acc0 = fmaf(h0, w2v[j], acc0);
            float h1 = bf2f(av1[j]) + bf2f(bv1[j]);
            h1 = fmaxf(h1, 0.f);
            acc1 = fmaf(h1, w2v[j], acc1);
        }
#pragma unroll
        for (int sh = 1; sh <= 8; sh <<= 1) {
            acc0 += __shfl_xor(acc0, sh);
            acc1 += __shfl_xor(acc1, sh);
        }
        if (lane16 == 0) {
            out[e0] = acc0 + b2v;
            if (has1) out[e1] = acc1 + b2v;
        }
    }
}

extern "C" void kernel_launch(void* const* d_in, const int* in_sizes, int n_in,
                              void* d_out, int out_size, void* d_ws, size_t ws_size,
                              hipStream_t stream) {
    const float* item = (const float*)d_in[0];
    const float* user = (const float*)d_in[1];
    const float* W1   = (const float*)d_in[2];
    const float* b1   = (const float*)d_in[3];
    const float* W2   = (const float*)d_in[4];
    const float* b2   = (const float*)d_in[5];
    const int*   src  = (const int*)d_in[6];
    const int*   dst  = (const int*)d_in[7];
    float* out = (float*)d_out;

    const int n_nodes = in_sizes[0] / NFEATS;
    const int n_edges = in_sizes[6];

    short* A = (short*)d_ws;                         // [n_nodes][128] bf16
    short* B = A + (size_t)n_nodes * NFEATS;         // [n_nodes][128] bf16

    dim3 grid(256, 2);                               // 512 blocks = 2/CU resident
    precompute_kernel<<<grid, 512, 0, stream>>>(item, user, W1, b1, A, B, n_nodes);

    edge_kernel<<<2048, 256, 0, stream>>>(A, B, src, dst, W2, b2, out, n_edges);
}